// Round 2
// baseline (77.725 us; speedup 1.0000x reference)
//
#include <hip/hip_runtime.h>

// LatticeQuantizer: HNLQ with binary codebook {0,1}^8.
// Nearest-codeword under L2 is separable: bit_d = (x/scale + zp > 0.5).
// Tie (==0.5) -> bit 0, matching argmin lowest-index tie-break.
// Outputs: quantized [N,8] fp32 (weighted sum of per-layer codewords),
//          indices  [N,3] stored as float32 of the integer index.

__global__ __launch_bounds__(256) void lq_kernel(
    const float* __restrict__ x,
    const float* __restrict__ scales,
    const int*   __restrict__ zps,
    const float* __restrict__ wts,
    float* __restrict__ outq,
    float* __restrict__ outi,
    int n)
{
    int row = blockIdx.x * blockDim.x + threadIdx.x;
    if (row >= n) return;

    const float4* xp = reinterpret_cast<const float4*>(x) + (size_t)row * 2;
    float4 a = xp[0];
    float4 b = xp[1];
    float xs[8] = {a.x, a.y, a.z, a.w, b.x, b.y, b.z, b.w};

    float q[8];
    #pragma unroll
    for (int d = 0; d < 8; ++d) q[d] = 0.0f;

    float idxf[3];
    #pragma unroll
    for (int l = 0; l < 3; ++l) {
        float s  = scales[l];
        float zp = (float)zps[l];
        float wt = wts[l];
        float rs = 1.0f / s;   // scales are powers of two -> exact reciprocal
        unsigned idx = 0u;
        #pragma unroll
        for (int d = 0; d < 8; ++d) {
            float xn = xs[d] * rs + zp;
            bool bit = xn > 0.5f;          // strict: tie keeps bit 0 (lower codeword index)
            if (bit) {
                idx |= 1u << (7 - d);       // MSB-first, matches format(i,'08b')
                q[d] += wt;                 // codeword element is 1 -> add layer weight
            }
        }
        idxf[l] = (float)idx;
    }

    float4 o0 = make_float4(q[0], q[1], q[2], q[3]);
    float4 o1 = make_float4(q[4], q[5], q[6], q[7]);
    float4* op = reinterpret_cast<float4*>(outq) + (size_t)row * 2;
    op[0] = o0;
    op[1] = o1;

    outi[(size_t)row * 3 + 0] = idxf[0];
    outi[(size_t)row * 3 + 1] = idxf[1];
    outi[(size_t)row * 3 + 2] = idxf[2];
}

extern "C" void kernel_launch(void* const* d_in, const int* in_sizes, int n_in,
                              void* d_out, int out_size, void* d_ws, size_t ws_size,
                              hipStream_t stream) {
    const float* x      = (const float*)d_in[0];
    // d_in[1] = codebook: binary structure exploited analytically, not read.
    const float* scales = (const float*)d_in[2];
    const int*   zps    = (const int*)d_in[3];
    const float* wts    = (const float*)d_in[4];

    int n = in_sizes[0] / 8;   // 524288 rows
    float* outq = (float*)d_out;                       // [n, 8]
    float* outi = (float*)d_out + (size_t)n * 8;       // [n, 3] as float

    const int block = 256;
    const int grid = (n + block - 1) / block;
    lq_kernel<<<grid, block, 0, stream>>>(x, scales, zps, wts, outq, outi, n);
}